// Round 15
// baseline (72.987 us; speedup 1.0000x reference)
//
#include <hip/hip_runtime.h>
#include <hip/hip_bf16.h>
#include <math.h>

#define B_ROWS 16384
#define DIM 1024

typedef __attribute__((ext_vector_type(8))) short s16x8;
typedef __attribute__((ext_vector_type(4))) float f32x4;

static __device__ __forceinline__ unsigned short f2bf(float f) {
    union { float f; unsigned u; } v; v.f = f;
    unsigned r = v.u + 0x7FFF + ((v.u >> 16) & 1);  // RNE
    return (unsigned short)(r >> 16);
}

// f32 -> fp8 e4m3fn (OCP), RNE, saturating.  Manual (no builtin dependency).
static __device__ __forceinline__ unsigned f2fp8(float f) {
    union { float f; unsigned u; } v; v.f = f;
    const unsigned s = (v.u >> 24) & 0x80u;
    const float a = fabsf(f);
    if (a >= 448.f) return s | 0x7Eu;          // max finite 448
    if (a < 0.015625f) {                       // subnormal, ulp 2^-9
        const int q = (int)rintf(a * 512.f);   // 0..8 (8 -> 0x08 = 2^-6, correct)
        return s | (unsigned)q;
    }
    unsigned b = v.u & 0x7fffffffu;
    b += 0x000FFFFFu + ((b >> 20) & 1u);       // RNE to 3 mantissa bits
    const int e = (int)(b >> 23) - 127;
    const unsigned m = (b >> 20) & 7u;
    return s | (unsigned)((e + 7) << 3) | m;
}

// async global -> LDS, 16 bytes per lane; lds base wave-uniform, HW adds lane*16
static __device__ __forceinline__ void gload16(const void* g, void* l) {
    __builtin_amdgcn_global_load_lds(
        (const __attribute__((address_space(1))) unsigned int*)g,
        (__attribute__((address_space(3))) unsigned int*)l, 16, 0, 0);
}

// ---------------------------------------------------------------------------
// prep_w (177 blocks): weight transpose+convert+pad via 64x64 LDS tiles.
//   blocks 0-127:  W1 (1024x500 f32) -> W1q (512x1024 fp8 e4m3, N x K),
//                  values PRE-SCALED x64 (keeps 0.01-scale weights normal in
//                  e4m3); rows >=500 zero.  GEMM epilogue multiplies by 1/64.
//   blocks 128-159: W2 -> W2b (256x512 bf16), 160-175: W3 -> W3b (256x256).
//   block 176: cross-net scalar constants czz[6] (f32 exact):
//     czz = {C2_0,C1_0,C0_0, C2_1,C1_1,C0_1}, C2=sum(w2w3b1wl), C1=sum(w3b2wl),
//     C0=sum(b3wl).
// ---------------------------------------------------------------------------
__global__ __launch_bounds__(256) void prep_w(
    const float* __restrict__ W1, const float* __restrict__ W2,
    const float* __restrict__ W3,
    const float* __restrict__ cw, const float* __restrict__ cb,
    const float* __restrict__ Wl,
    unsigned char* __restrict__ W1q,
    unsigned short* __restrict__ W2b, unsigned short* __restrict__ W3b,
    float* __restrict__ czz) {
    __shared__ unsigned short tile[64][72];
    __shared__ unsigned char tilec[64][72];
    __shared__ float red[4][6];
    const int tid = threadIdx.x;
    const int blk = blockIdx.x;

    if (blk < 128) {
        // ---- W1 -> fp8 x64, transposed ----
        const int kt = blk & 15, nt = blk >> 4;
        const int k0 = kt << 6, n0 = nt << 6;
        {
            const int r = tid >> 2, c0 = (tid & 3) << 4;
            const int kk = k0 + r;
#pragma unroll
            for (int i = 0; i < 16; ++i) {
                const int nn = n0 + c0 + i;
                const float v = (nn < 500) ? W1[(size_t)kk * 500 + nn] * 64.f : 0.f;
                tilec[r][c0 + i] = (unsigned char)f2fp8(v);
            }
        }
        __syncthreads();
        {
            const int n = tid >> 2, kc = (tid & 3) << 4;
            unsigned char* o = W1q + (size_t)(n0 + n) * 1024 + k0 + kc;
#pragma unroll
            for (int i = 0; i < 16; ++i) o[i] = tilec[kc + i][n];
        }
    } else if (blk < 176) {
        const int w = blk;
        const float* src; unsigned short* dst;
        int kt, nt, Ksrc, Nsrc, ldDst;
        if (w < 160) { kt = (w - 128) & 7;  nt = (w - 128) >> 3; src = W2; dst = W2b; Ksrc = 500; Nsrc = 200; ldDst = 512; }
        else         { kt = (w - 160) & 3;  nt = (w - 160) >> 2; src = W3; dst = W3b; Ksrc = 200; Nsrc = 200; ldDst = 256; }
        const int k0 = kt << 6, n0 = nt << 6;
        {
            const int r = tid >> 2, c0 = (tid & 3) << 4;
            const int kk = k0 + r;
#pragma unroll
            for (int i = 0; i < 16; ++i) {
                const int nn = n0 + c0 + i;
                const float v = (kk < Ksrc && nn < Nsrc) ? src[(size_t)kk * Nsrc + nn] : 0.f;
                tile[r][c0 + i] = f2bf(v);
            }
        }
        __syncthreads();
        {
            const int n = tid >> 2, kc = (tid & 3) << 4;
            unsigned short* o = dst + (size_t)(n0 + n) * ldDst + k0 + kc;
#pragma unroll
            for (int i = 0; i < 16; ++i) o[i] = tile[kc + i][n];
        }
    } else {
        // ---- czz scalars (f32 exact) ----
        float c[6] = {0.f, 0.f, 0.f, 0.f, 0.f, 0.f};
#pragma unroll
        for (int q = 0; q < 4; ++q) {
            const int k = tid * 4 + q;
            const float wl = Wl[k];
            {
                const float w2 = cw[1024 + k], w3 = cw[2048 + k];
                const float b1 = cb[k], b2 = cb[1024 + k], b3 = cb[2048 + k];
                c[0] += w2 * w3 * b1 * wl;
                c[1] += w3 * b2 * wl;
                c[2] += b3 * wl;
            }
            {
                const float w2 = cw[4096 + k], w3 = cw[5120 + k];
                const float b1 = cb[3072 + k], b2 = cb[4096 + k], b3 = cb[5120 + k];
                c[3] += w2 * w3 * b1 * wl;
                c[4] += w3 * b2 * wl;
                c[5] += b3 * wl;
            }
        }
        const int lane = tid & 63, wv = tid >> 6;
#pragma unroll
        for (int j = 0; j < 6; ++j)
#pragma unroll
            for (int m = 1; m < 64; m <<= 1) c[j] += __shfl_xor(c[j], m, 64);
        if (lane == 0)
#pragma unroll
            for (int j = 0; j < 6; ++j) red[wv][j] = c[j];
        __syncthreads();
        if (tid < 6) czz[tid] = red[0][tid] + red[1][tid] + red[2][tid] + red[3][tid];
    }
}

// ---------------------------------------------------------------------------
// xdots (1024 blocks x 256): streams x ONCE in f32.  Per row computes the 8
// cross-net reductions EXACTLY in f32:
//   zp = {x.P3_0, x.P2_0, x.P1_0, x.P3_1, x.P2_1, x.P1_1, x.Wl, sum(x)}
// (P3=w1w2w3*wl, P2=w2w3*wl, P1=w3*wl computed on the fly), and emits the
// fp8 e4m3 copy of x for the MLP GEMM.  4 waves, 4 rows/wave, 16 rows/block.
// ---------------------------------------------------------------------------
__global__ __launch_bounds__(256) void xdots(
    const float* __restrict__ x,
    const float* __restrict__ cw, const float* __restrict__ Wl,
    unsigned char* __restrict__ xq,
    float* __restrict__ zparts) {
    const int tid  = threadIdx.x;
    const int lane = tid & 63;
    const int w    = tid >> 6;
    const int row0 = (blockIdx.x << 4) + (w << 2);

    float d[4][8];
#pragma unroll
    for (int r = 0; r < 4; ++r)
#pragma unroll
        for (int j = 0; j < 8; ++j) d[r][j] = 0.f;

#pragma unroll
    for (int c = 0; c < 4; ++c) {
        const int kb = c * 256 + lane * 4;
        const float4 wl4 = *(const float4*)(Wl + kb);
        const float4 c0 = *(const float4*)(cw + kb);
        const float4 c1 = *(const float4*)(cw + 1024 + kb);
        const float4 c2 = *(const float4*)(cw + 2048 + kb);
        const float4 c3 = *(const float4*)(cw + 3072 + kb);
        const float4 c4 = *(const float4*)(cw + 4096 + kb);
        const float4 c5 = *(const float4*)(cw + 5120 + kb);
        float4 p10, p20, p30, p11, p21, p31;
        p10.x = c2.x * wl4.x; p10.y = c2.y * wl4.y; p10.z = c2.z * wl4.z; p10.w = c2.w * wl4.w;
        p20.x = c1.x * p10.x; p20.y = c1.y * p10.y; p20.z = c1.z * p10.z; p20.w = c1.w * p10.w;
        p30.x = c0.x * p20.x; p30.y = c0.y * p20.y; p30.z = c0.z * p20.z; p30.w = c0.w * p20.w;
        p11.x = c5.x * wl4.x; p11.y = c5.y * wl4.y; p11.z = c5.z * wl4.z; p11.w = c5.w * wl4.w;
        p21.x = c4.x * p11.x; p21.y = c4.y * p11.y; p21.z = c4.z * p11.z; p21.w = c4.w * p11.w;
        p31.x = c3.x * p21.x; p31.y = c3.y * p21.y; p31.z = c3.z * p21.z; p31.w = c3.w * p21.w;

#pragma unroll
        for (int r = 0; r < 4; ++r) {
            const float4 xv = *(const float4*)(x + (size_t)(row0 + r) * DIM + kb);
            d[r][0] += xv.x * p30.x + xv.y * p30.y + xv.z * p30.z + xv.w * p30.w;
            d[r][1] += xv.x * p20.x + xv.y * p20.y + xv.z * p20.z + xv.w * p20.w;
            d[r][2] += xv.x * p10.x + xv.y * p10.y + xv.z * p10.z + xv.w * p10.w;
            d[r][3] += xv.x * p31.x + xv.y * p31.y + xv.z * p31.z + xv.w * p31.w;
            d[r][4] += xv.x * p21.x + xv.y * p21.y + xv.z * p21.z + xv.w * p21.w;
            d[r][5] += xv.x * p11.x + xv.y * p11.y + xv.z * p11.z + xv.w * p11.w;
            d[r][6] += xv.x * wl4.x + xv.y * wl4.y + xv.z * wl4.z + xv.w * wl4.w;
            d[r][7] += xv.x + xv.y + xv.z + xv.w;
            const unsigned u = f2fp8(xv.x) | (f2fp8(xv.y) << 8) |
                               (f2fp8(xv.z) << 16) | (f2fp8(xv.w) << 24);
            *(unsigned*)(xq + (size_t)(row0 + r) * DIM + kb) = u;
        }
    }

#pragma unroll
    for (int r = 0; r < 4; ++r)
#pragma unroll
        for (int j = 0; j < 8; ++j)
#pragma unroll
            for (int m = 1; m < 64; m <<= 1)
                d[r][j] += __shfl_xor(d[r][j], m, 64);

    if (lane == 0) {
#pragma unroll
        for (int r = 0; r < 4; ++r)
#pragma unroll
            for (int j = 0; j < 8; ++j)
                zparts[(size_t)(row0 + r) * 8 + j] = d[r][j];
    }
}

// ---------------------------------------------------------------------------
// stage_fp8: stage a 128-row x 128-byte fp8 tile via global_load_lds.
// LDS slot s (16B) of row holds global k-chunk (s ^ (row&7)); linear dest.
// ---------------------------------------------------------------------------
static __device__ __forceinline__ void stage_fp8(
    const unsigned char* __restrict__ src, int rowBase, int kt,
    unsigned char* lds, int w, int lane) {
    const int r8   = lane >> 3;
    const int slot = lane & 7;
#pragma unroll
    for (int q = 0; q < 4; ++q) {
        const int blk   = q * 4 + w;
        const int row   = blk * 8 + r8;
        const int chunk = slot ^ (row & 7);
        gload16(src + (size_t)(rowBase + row) * 1024 + kt * 128 + chunk * 16,
                lds + blk * 1024);
    }
}

// ---------------------------------------------------------------------------
// gemm_fp8: d1 = relu((xq @ W1q^T) * (1/64) + b1), fp8 e4m3 MFMA.
// Tile 128x128, BK=128 (nK=8), 4 waves (2x2), each wave 64x64 (acc 4x4).
// mfma_f32_16x16x32_fp8_fp8: 8B/lane fragments -> ds_read_b64 (half the LDS
// bytes/FLOP of bf16).  Both operands via global_load_lds, double-buffered,
// one barrier per K-step.  Epilogue: LDS-bounce coalesced stores.
// ---------------------------------------------------------------------------
__global__ __launch_bounds__(256) void gemm_fp8(
    const unsigned char* __restrict__ A,    // 16384 x 1024 fp8
    const unsigned char* __restrict__ Bq,   // 512 x 1024 fp8 (N x K), x64
    const float* __restrict__ bias,         // b1 (500)
    unsigned short* __restrict__ C) {       // 16384 x 512 bf16
    constexpr int nK = 8;
    __shared__ unsigned char As[2][128 * 128];   // 32 KB (reused as C bounce)
    __shared__ unsigned char Bs[2][128 * 128];   // 32 KB

    const int tid  = threadIdx.x;
    const int lane = tid & 63;
    const int wid  = tid >> 6;
    const int wm   = wid >> 1;
    const int wn   = wid & 1;
    const int g    = lane >> 4;
    const int r16  = lane & 15;

    const int cpx = gridDim.x >> 3;
    const int swz = (blockIdx.x & 7) * cpx + (blockIdx.x >> 3);
    const int rowBase = (swz >> 2) << 7;       // 4 col tiles (512/128)
    const int colBase = (swz & 3) << 7;

    f32x4 acc[4][4];
#pragma unroll
    for (int m = 0; m < 4; ++m)
#pragma unroll
        for (int n = 0; n < 4; ++n)
            acc[m][n] = (f32x4){0.f, 0.f, 0.f, 0.f};

    stage_fp8(A, rowBase, 0, As[0], wid, lane);
    stage_fp8(Bq, colBase, 0, Bs[0], wid, lane);
    asm volatile("s_waitcnt vmcnt(0)" ::: "memory");
    __builtin_amdgcn_s_barrier();
    asm volatile("" ::: "memory");

    for (int kt = 0; kt < nK; ++kt) {
        const int buf = kt & 1;
        if (kt + 1 < nK) {
            stage_fp8(A, rowBase, kt + 1, As[buf ^ 1], wid, lane);
            stage_fp8(Bq, colBase, kt + 1, Bs[buf ^ 1], wid, lane);
        }
        asm volatile("" ::: "memory");

        const unsigned char* Ab = As[buf];
        const unsigned char* Bb = Bs[buf];
#pragma unroll
        for (int ks = 0; ks < 4; ++ks) {
            long af[4], bf[4];
#pragma unroll
            for (int m = 0; m < 4; ++m) {
                const int row = wm * 64 + m * 16 + r16;
                const int byte = row * 128 +
                    ((((ks << 1) | (g >> 1)) ^ (row & 7)) << 4) + ((g & 1) << 3);
                af[m] = *(const long*)(Ab + byte);
            }
#pragma unroll
            for (int n = 0; n < 4; ++n) {
                const int row = wn * 64 + n * 16 + r16;
                const int byte = row * 128 +
                    ((((ks << 1) | (g >> 1)) ^ (row & 7)) << 4) + ((g & 1) << 3);
                bf[n] = *(const long*)(Bb + byte);
            }
#pragma unroll
            for (int m = 0; m < 4; ++m)
#pragma unroll
                for (int n = 0; n < 4; ++n)
                    acc[m][n] = __builtin_amdgcn_mfma_f32_16x16x32_fp8_fp8(
                        af[m], bf[n], acc[m][n], 0, 0, 0);
        }

        asm volatile("s_waitcnt vmcnt(0)" ::: "memory");
        __builtin_amdgcn_s_barrier();
        asm volatile("" ::: "memory");
    }

    // ---- epilogue: 1/64 scale + bias + relu -> LDS bounce ----
    unsigned short* Cb = (unsigned short*)As[0];   // 32 KB = 128x128 bf16
#pragma unroll
    for (int n = 0; n < 4; ++n) {
        const int lcol = wn * 64 + n * 16 + r16;
        const int col = colBase + lcol;
        const float bv = (col < 500) ? bias[col] : 0.f;
#pragma unroll
        for (int m = 0; m < 4; ++m) {
            const int lrow = wm * 64 + m * 16 + g * 4;
#pragma unroll
            for (int r = 0; r < 4; ++r) {
                float v = acc[m][n][r] * 0.015625f + bv;
                v = v > 0.f ? v : 0.f;
                Cb[(lrow + r) * 128 + lcol] = f2bf(v);
            }
        }
    }
    __syncthreads();

    // coalesced copy-out: thread t -> row t>>1, 64-col half t&1 (128B)
    {
        const int row  = tid >> 1;
        const int half = tid & 1;
        const uint4* s = (const uint4*)(Cb + row * 128 + half * 64);
        uint4* dd = (uint4*)(C + (size_t)(rowBase + row) * 512 + colBase + half * 64);
        dd[0] = s[0]; dd[1] = s[1]; dd[2] = s[2]; dd[3] = s[3];
    }
}

// ---------------------------------------------------------------------------
// stage8 (8-wave bf16 staging for tail_fused, unchanged)
// ---------------------------------------------------------------------------
template <int ROWS>
static __device__ __forceinline__ void stage8(
    const unsigned short* __restrict__ src, int K, int rowBase, int kt,
    unsigned short* lds, int w, int lane) {
    const int r8   = lane >> 3;
    const int slot = lane & 7;
#pragma unroll
    for (int q = 0; q < ROWS / 64; ++q) {
        const int blk   = q * 8 + w;
        const int row   = blk * 8 + r8;
        const int chunk = slot ^ (row & 7);
        gload16(src + (size_t)(rowBase + row) * K + kt * 64 + chunk * 8,
                lds + blk * 512);
    }
}

// ---------------------------------------------------------------------------
// tail_fused (unchanged from R9-13): per 64-row block —
//   phase 1: P = relu(d1[64x512] @ W2b^T + b2); phase 2: acc2 = P @ W3b^T;
//   tail = relu(acc2+b3).Wl[1024:]; z_i = Horner(zparts,s)+czz_i+tail+bl.
// ---------------------------------------------------------------------------
__global__ __launch_bounds__(512) void tail_fused(
    const unsigned short* __restrict__ d1,
    const unsigned short* __restrict__ W2b, const float* __restrict__ b2,
    const unsigned short* __restrict__ W3b, const float* __restrict__ b3,
    const float* __restrict__ Wl, const float* __restrict__ bl,
    const float* __restrict__ zparts, const float* __restrict__ czz,
    float* __restrict__ out) {
    __shared__ unsigned short As[2][64 * 64];
    __shared__ unsigned short Bs[2][256 * 64];
    __shared__ unsigned short P[64 * 256];
    __shared__ float part[8][64];

    const int tid  = threadIdx.x;
    const int lane = tid & 63;
    const int wid  = tid >> 6;
    const int wm   = wid >> 2;
    const int wn   = wid & 3;
    const int g    = lane >> 4;
    const int r16  = lane & 15;
    const int rowBase = blockIdx.x << 6;

    f32x4 acc[2][4];
#pragma unroll
    for (int m = 0; m < 2; ++m)
#pragma unroll
        for (int n = 0; n < 4; ++n)
            acc[m][n] = (f32x4){0.f, 0.f, 0.f, 0.f};

    stage8<64>(d1, 512, rowBase, 0, As[0], wid, lane);
    stage8<256>(W2b, 512, 0, 0, Bs[0], wid, lane);

    for (int kt = 0; kt < 8; ++kt) {
        const int buf = kt & 1;
        if (kt + 1 < 8) {
            stage8<64>(d1, 512, rowBase, kt + 1, As[buf ^ 1], wid, lane);
            stage8<256>(W2b, 512, 0, kt + 1, Bs[buf ^ 1], wid, lane);
            asm volatile("s_waitcnt vmcnt(5)" ::: "memory");
        } else {
            asm volatile("s_waitcnt vmcnt(0)" ::: "memory");
        }
        __builtin_amdgcn_s_barrier();
        asm volatile("" ::: "memory");

        const unsigned short* Ab = As[buf];
        const unsigned short* Bb = Bs[buf];
#pragma unroll
        for (int ks = 0; ks < 2; ++ks) {
            s16x8 af[2], bfr[4];
#pragma unroll
            for (int m = 0; m < 2; ++m) {
                const int row = wm * 32 + m * 16 + r16;
                const int off = ((ks * 4 + g) * 16) ^ ((row & 7) << 4);
                af[m] = *(const s16x8*)((const char*)Ab + row * 128 + off);
            }
#pragma unroll
            for (int n = 0; n < 4; ++n) {
                const int row = wn * 64 + n * 16 + r16;
                const int off = ((ks * 4 + g) * 16) ^ ((row & 7) << 4);
                bfr[n] = *(const s16x8*)((const char*)Bb + row * 128 + off);
            }
#pragma unroll
            for (int m = 0; m < 2; ++m)
#pragma unroll
                for (int n = 0; n < 4; ++n)
                    acc[m][n] = __builtin_amdgcn_mfma_f32_16x16x32_bf16(af[m], bfr[n], acc[m][n], 0, 0, 0);
        }
        asm volatile("s_waitcnt lgkmcnt(0)" ::: "memory");
        __builtin_amdgcn_s_barrier();
        asm volatile("" ::: "memory");
    }

#pragma unroll
    for (int n = 0; n < 4; ++n) {
        const int col = wn * 64 + n * 16 + r16;
        const float bv = (col < 200) ? b2[col] : 0.f;
#pragma unroll
        for (int m = 0; m < 2; ++m) {
#pragma unroll
            for (int r = 0; r < 4; ++r) {
                const int row = wm * 32 + m * 16 + g * 4 + r;
                float v = acc[m][n][r] + bv;
                v = v > 0.f ? v : 0.f;
                const int byte = row * 512 + ((col * 2) ^ ((row & 7) << 4));
                *(unsigned short*)((char*)P + byte) = f2bf(v);
            }
        }
    }

    stage8<256>(W3b, 256, 0, 0, Bs[0], wid, lane);
    asm volatile("s_waitcnt lgkmcnt(0)" ::: "memory");
    __builtin_amdgcn_s_barrier();
    asm volatile("" ::: "memory");

    f32x4 acc2[2][4];
#pragma unroll
    for (int m = 0; m < 2; ++m)
#pragma unroll
        for (int n = 0; n < 4; ++n)
            acc2[m][n] = (f32x4){0.f, 0.f, 0.f, 0.f};

    for (int kt = 0; kt < 4; ++kt) {
        const int buf = kt & 1;
        if (kt + 1 < 4) {
            stage8<256>(W3b, 256, 0, kt + 1, Bs[buf ^ 1], wid, lane);
            asm volatile("s_waitcnt vmcnt(4)" ::: "memory");
        } else {
            asm volatile("s_waitcnt vmcnt(0)" ::: "memory");
        }
        __builtin_amdgcn_s_barrier();
        asm volatile("" ::: "memory");

        const unsigned short* Bb = Bs[buf];
#pragma unroll
        for (int ks = 0; ks < 2; ++ks) {
            s16x8 af[2], bfr[4];
#pragma unroll
            for (int m = 0; m < 2; ++m) {
                const int row = wm * 32 + m * 16 + r16;
                const int byte = row * 512 + ((kt * 128 + (ks * 4 + g) * 16) ^ ((row & 7) << 4));
                af[m] = *(const s16x8*)((const char*)P + byte);
            }
#pragma unroll
            for (int n = 0; n < 4; ++n) {
                const int row = wn * 64 + n * 16 + r16;
                const int off = ((ks * 4 + g) * 16) ^ ((row & 7) << 4);
                bfr[n] = *(const s16x8*)((const char*)Bb + row * 128 + off);
            }
#pragma unroll
            for (int m = 0; m < 2; ++m)
#pragma unroll
                for (int n = 0; n < 4; ++n)
                    acc2[m][n] = __builtin_amdgcn_mfma_f32_16x16x32_bf16(af[m], bfr[n], acc2[m][n], 0, 0, 0);
        }
        asm volatile("s_waitcnt lgkmcnt(0)" ::: "memory");
        __builtin_amdgcn_s_barrier();
        asm volatile("" ::: "memory");
    }

    float wlv[4], b3v[4];
#pragma unroll
    for (int n = 0; n < 4; ++n) {
        const int col = wn * 64 + n * 16 + r16;
        wlv[n] = (col < 200) ? Wl[1024 + col] : 0.f;
        b3v[n] = (col < 200) ? b3[col] : 0.f;
    }
#pragma unroll
    for (int m = 0; m < 2; ++m) {
#pragma unroll
        for (int r = 0; r < 4; ++r) {
            float s = 0.f;
#pragma unroll
            for (int n = 0; n < 4; ++n) {
                float v = acc2[m][n][r] + b3v[n];
                v = v > 0.f ? v : 0.f;
                s += v * wlv[n];
            }
            s += __shfl_xor(s, 1, 64);
            s += __shfl_xor(s, 2, 64);
            s += __shfl_xor(s, 4, 64);
            s += __shfl_xor(s, 8, 64);
            if (r16 == 0) part[wid][wm * 32 + m * 16 + g * 4 + r] = s;
        }
    }
    __syncthreads();

    if (tid < 64) {
        const int row = rowBase + tid;
        const int wmr = (tid >> 5) << 2;
        const float t = part[wmr][tid] + part[wmr + 1][tid] +
                        part[wmr + 2][tid] + part[wmr + 3][tid];
        const float blv = bl[0];
        const float* zp = zparts + (size_t)row * 8;
        float4 zpa = *(const float4*)(zp);       // P3_0 P2_0 P1_0 P3_1
        float4 zpb = *(const float4*)(zp + 4);   // P2_1 P1_1 P0   s
        const float s = zpb.w;
        const float z0 = ((zpa.x * s + zpa.y + czz[0]) * s + zpa.z + czz[1]) * s
                         + zpb.z + czz[2] + t + blv;
        const float z1 = ((zpa.w * s + zpb.x + czz[3]) * s + zpb.y + czz[4]) * s
                         + zpb.z + czz[5] + t + blv;
        out[row]          = 1.f / (1.f + expf(-z0));
        out[B_ROWS + row] = 1.f / (1.f + expf(-z1));
    }
}

// ---------------------------------------------------------------------------
extern "C" void kernel_launch(void* const* d_in, const int* in_sizes, int n_in,
                              void* d_out, int out_size, void* d_ws, size_t ws_size,
                              hipStream_t stream) {
    const float* x  = (const float*)d_in[0];
    const float* W1 = (const float*)d_in[3];
    const float* b1 = (const float*)d_in[4];
    const float* W2 = (const float*)d_in[5];
    const float* b2 = (const float*)d_in[6];
    const float* W3 = (const float*)d_in[7];
    const float* b3 = (const float*)d_in[8];
    const float* Wl = (const float*)d_in[9];
    const float* bl = (const float*)d_in[10];
    const float* cw = (const float*)d_in[11];
    const float* cb = (const float*)d_in[12];
    float* out = (float*)d_out;

    unsigned short* d1  = (unsigned short*)d_ws;          // 16384 x 512 bf16
    unsigned char*  xq  = (unsigned char*)(d1 + (size_t)16384 * 512);  // 16384 x 1024 fp8
    unsigned char*  W1q = xq + (size_t)16384 * 1024;      // 512 x 1024 fp8
    unsigned short* W2b = (unsigned short*)(W1q + (size_t)512 * 1024); // 256 x 512
    unsigned short* W3b = W2b + (size_t)256 * 512;        // 256 x 256
    float* zparts = (float*)(W3b + (size_t)256 * 256);    // 16384 x 8
    float* czz = zparts + (size_t)16384 * 8;              // 6

    // weight transpose/convert (W1 -> fp8 x64) + cross-net scalars
    prep_w<<<177, 256, 0, stream>>>(W1, W2, W3, cw, cb, Wl, W1q, W2b, W3b, czz);

    // x -> fp8 + exact f32 cross-net dots (x read once, f32)
    xdots<<<1024, 256, 0, stream>>>(x, cw, Wl, xq, zparts);

    // d1 = relu((xq @ W1q) / 64 + b1), fp8 MFMA
    gemm_fp8<<<512, 256, 0, stream>>>(xq, W1q, b1, d1);

    // d2/d3/tail/cross-combine/sigmoid fused
    tail_fused<<<256, 512, 0, stream>>>(d1, W2b, b2, W3b, b3, Wl, bl,
                                        zparts, czz, out);
}

// Round 16
// 54.443 us; speedup vs baseline: 1.3406x; 1.3406x over previous
//
#include <hip/hip_runtime.h>
#include <hip/hip_bf16.h>
#include <math.h>

#define B_ROWS 16384
#define DIM 1024

typedef __attribute__((ext_vector_type(8))) short s16x8;
typedef __attribute__((ext_vector_type(4))) float f32x4;

static __device__ __forceinline__ unsigned short f2bf(float f) {
    union { float f; unsigned u; } v; v.f = f;
    unsigned r = v.u + 0x7FFF + ((v.u >> 16) & 1);  // RNE
    return (unsigned short)(r >> 16);
}

// f32 -> fp8 e4m3fn scalar (cold path: weight conversion only)
static __device__ __forceinline__ unsigned f2fp8(float f) {
    union { float f; unsigned u; } v; v.f = f;
    const unsigned s = (v.u >> 24) & 0x80u;
    const float a = fabsf(f);
    if (a >= 448.f) return s | 0x7Eu;
    if (a < 0.015625f) {
        const int q = (int)rintf(a * 512.f);
        return s | (unsigned)q;
    }
    unsigned b = v.u & 0x7fffffffu;
    b += 0x000FFFFFu + ((b >> 20) & 1u);
    const int e = (int)(b >> 23) - 127;
    const unsigned m = (b >> 20) & 7u;
    return s | (unsigned)((e + 7) << 3) | m;
}

// NATIVE packed f32x4 -> fp8x4 (hot path): two v_cvt_pk_fp8_f32, RNE+saturate.
static __device__ __forceinline__ unsigned cvt4_fp8(float a, float b, float c, float d) {
    unsigned u;
    asm volatile("v_cvt_pk_fp8_f32 %0, %1, %2\n\t"
                 "v_cvt_pk_fp8_f32 %0, %3, %4 op_sel:[0,0,1]"
                 : "=v"(u) : "v"(a), "v"(b), "v"(c), "v"(d));
    return u;
}

// async global -> LDS, 16 bytes per lane; lds base wave-uniform
static __device__ __forceinline__ void gload16(const void* g, void* l) {
    __builtin_amdgcn_global_load_lds(
        (const __attribute__((address_space(1))) unsigned int*)g,
        (__attribute__((address_space(3))) unsigned int*)l, 16, 0, 0);
}

// ---------------------------------------------------------------------------
// xdots_prep (2225 blocks):
//  blocks [0,128):   W1 (1024x500) -> W1q (512x1024 fp8 e4m3 N x K, x64 scale)
//  blocks [128,176): W2 -> W2b bf16, W3 -> W3b bf16 (transposed, padded)
//  block 176:        czz[6] cross-net scalar constants (f32 exact)
//  blocks [177,2225): x rows — per row the 8 EXACT f32 cross-net reductions
//    zp = {x.P3_0,x.P2_0,x.P1_0, x.P3_1,x.P2_1,x.P1_1, x.Wl, sum(x)}
//    plus the fp8 e4m3 copy of x (native cvt).  4 waves x 2 rows = 8 rows/blk.
// ---------------------------------------------------------------------------
__global__ __launch_bounds__(256, 5) void xdots_prep(
    const float* __restrict__ x,
    const float* __restrict__ W1, const float* __restrict__ W2,
    const float* __restrict__ W3,
    const float* __restrict__ cw, const float* __restrict__ cb,
    const float* __restrict__ Wl,
    unsigned char* __restrict__ W1q,
    unsigned short* __restrict__ W2b, unsigned short* __restrict__ W3b,
    float* __restrict__ czz,
    unsigned char* __restrict__ xq,
    float* __restrict__ zparts) {
    __shared__ unsigned short tile[64][72];
    __shared__ unsigned char tilec[64][72];
    __shared__ float red[4][6];
    const int tid  = threadIdx.x;
    const int lane = tid & 63;
    const int w    = tid >> 6;
    const int blk  = blockIdx.x;

    if (blk < 128) {
        // ---- W1 -> fp8 x64, transposed ----
        const int kt = blk & 15, nt = blk >> 4;
        const int k0 = kt << 6, n0 = nt << 6;
        {
            const int r = tid >> 2, c0 = (tid & 3) << 4;
            const int kk = k0 + r;
#pragma unroll
            for (int i = 0; i < 16; ++i) {
                const int nn = n0 + c0 + i;
                const float v = (nn < 500) ? W1[(size_t)kk * 500 + nn] * 64.f : 0.f;
                tilec[r][c0 + i] = (unsigned char)f2fp8(v);
            }
        }
        __syncthreads();
        {
            const int n = tid >> 2, kc = (tid & 3) << 4;
            unsigned char* o = W1q + (size_t)(n0 + n) * 1024 + k0 + kc;
#pragma unroll
            for (int i = 0; i < 16; ++i) o[i] = tilec[kc + i][n];
        }
        return;
    } else if (blk < 176) {
        const float* src; unsigned short* dst;
        int kt, nt, Ksrc, Nsrc, ldDst;
        if (blk < 160) { kt = (blk - 128) & 7;  nt = (blk - 128) >> 3; src = W2; dst = W2b; Ksrc = 500; Nsrc = 200; ldDst = 512; }
        else           { kt = (blk - 160) & 3;  nt = (blk - 160) >> 2; src = W3; dst = W3b; Ksrc = 200; Nsrc = 200; ldDst = 256; }
        const int k0 = kt << 6, n0 = nt << 6;
        {
            const int r = tid >> 2, c0 = (tid & 3) << 4;
            const int kk = k0 + r;
#pragma unroll
            for (int i = 0; i < 16; ++i) {
                const int nn = n0 + c0 + i;
                const float v = (kk < Ksrc && nn < Nsrc) ? src[(size_t)kk * Nsrc + nn] : 0.f;
                tile[r][c0 + i] = f2bf(v);
            }
        }
        __syncthreads();
        {
            const int n = tid >> 2, kc = (tid & 3) << 4;
            unsigned short* o = dst + (size_t)(n0 + n) * ldDst + k0 + kc;
#pragma unroll
            for (int i = 0; i < 16; ++i) o[i] = tile[kc + i][n];
        }
        return;
    } else if (blk == 176) {
        float c[6] = {0.f, 0.f, 0.f, 0.f, 0.f, 0.f};
#pragma unroll
        for (int q = 0; q < 4; ++q) {
            const int k = tid * 4 + q;
            const float wl = Wl[k];
            {
                const float w2 = cw[1024 + k], w3 = cw[2048 + k];
                const float b1 = cb[k], b2 = cb[1024 + k], b3 = cb[2048 + k];
                c[0] += w2 * w3 * b1 * wl;
                c[1] += w3 * b2 * wl;
                c[2] += b3 * wl;
            }
            {
                const float w2 = cw[4096 + k], w3 = cw[5120 + k];
                const float b1 = cb[3072 + k], b2 = cb[4096 + k], b3 = cb[5120 + k];
                c[3] += w2 * w3 * b1 * wl;
                c[4] += w3 * b2 * wl;
                c[5] += b3 * wl;
            }
        }
#pragma unroll
        for (int j = 0; j < 6; ++j)
#pragma unroll
            for (int m = 1; m < 64; m <<= 1) c[j] += __shfl_xor(c[j], m, 64);
        if (lane == 0)
#pragma unroll
            for (int j = 0; j < 6; ++j) red[w][j] = c[j];
        __syncthreads();
        if (tid < 6) czz[tid] = red[0][tid] + red[1][tid] + red[2][tid] + red[3][tid];
        return;
    }

    // ---- x path: 2 rows per wave ----
    const int row0 = (blk - 177) * 8 + (w << 1);
    float d[2][8];
#pragma unroll
    for (int r = 0; r < 2; ++r)
#pragma unroll
        for (int j = 0; j < 8; ++j) d[r][j] = 0.f;

#pragma unroll
    for (int c = 0; c < 4; ++c) {
        const int kb = c * 256 + lane * 4;
        const float4 wl4 = *(const float4*)(Wl + kb);
        const float4 c0 = *(const float4*)(cw + kb);
        const float4 c1 = *(const float4*)(cw + 1024 + kb);
        const float4 c2 = *(const float4*)(cw + 2048 + kb);
        const float4 c3 = *(const float4*)(cw + 3072 + kb);
        const float4 c4 = *(const float4*)(cw + 4096 + kb);
        const float4 c5 = *(const float4*)(cw + 5120 + kb);
        const float4 xv0 = *(const float4*)(x + (size_t)row0 * DIM + kb);
        const float4 xv1 = *(const float4*)(x + (size_t)(row0 + 1) * DIM + kb);

        const float* wlp = (const float*)&wl4;
        const float* p0 = (const float*)&c0; const float* p1 = (const float*)&c1;
        const float* p2 = (const float*)&c2; const float* p3 = (const float*)&c3;
        const float* p4 = (const float*)&c4; const float* p5 = (const float*)&c5;
        const float* xa = (const float*)&xv0; const float* xb = (const float*)&xv1;
#pragma unroll
        for (int q = 0; q < 4; ++q) {
            const float wl  = wlp[q];
            const float pa1 = p2[q] * wl;
            const float pa2 = p1[q] * pa1;
            const float pa3 = p0[q] * pa2;
            const float pb1 = p5[q] * wl;
            const float pb2 = p4[q] * pb1;
            const float pb3 = p3[q] * pb2;
            const float a = xa[q], b = xb[q];
            d[0][0] = fmaf(a, pa3, d[0][0]);
            d[0][1] = fmaf(a, pa2, d[0][1]);
            d[0][2] = fmaf(a, pa1, d[0][2]);
            d[0][3] = fmaf(a, pb3, d[0][3]);
            d[0][4] = fmaf(a, pb2, d[0][4]);
            d[0][5] = fmaf(a, pb1, d[0][5]);
            d[0][6] = fmaf(a, wl,  d[0][6]);
            d[0][7] += a;
            d[1][0] = fmaf(b, pa3, d[1][0]);
            d[1][1] = fmaf(b, pa2, d[1][1]);
            d[1][2] = fmaf(b, pa1, d[1][2]);
            d[1][3] = fmaf(b, pb3, d[1][3]);
            d[1][4] = fmaf(b, pb2, d[1][4]);
            d[1][5] = fmaf(b, pb1, d[1][5]);
            d[1][6] = fmaf(b, wl,  d[1][6]);
            d[1][7] += b;
        }
        *(unsigned*)(xq + (size_t)row0 * DIM + kb)       = cvt4_fp8(xa[0], xa[1], xa[2], xa[3]);
        *(unsigned*)(xq + (size_t)(row0 + 1) * DIM + kb) = cvt4_fp8(xb[0], xb[1], xb[2], xb[3]);
    }

#pragma unroll
    for (int r = 0; r < 2; ++r)
#pragma unroll
        for (int j = 0; j < 8; ++j)
#pragma unroll
            for (int m = 1; m < 64; m <<= 1)
                d[r][j] += __shfl_xor(d[r][j], m, 64);

    if (lane == 0) {
#pragma unroll
        for (int r = 0; r < 2; ++r) {
            float4 za = {d[r][0], d[r][1], d[r][2], d[r][3]};
            float4 zb = {d[r][4], d[r][5], d[r][6], d[r][7]};
            *(float4*)(zparts + (size_t)(row0 + r) * 8)     = za;
            *(float4*)(zparts + (size_t)(row0 + r) * 8 + 4) = zb;
        }
    }
}

// ---------------------------------------------------------------------------
// stage_fp8: stage a 128-row x 128-byte fp8 tile via global_load_lds.
// LDS slot s (16B) of row holds global k-chunk (s ^ (row&7)); linear dest.
// ---------------------------------------------------------------------------
static __device__ __forceinline__ void stage_fp8(
    const unsigned char* __restrict__ src, int rowBase, int kt,
    unsigned char* lds, int w, int lane) {
    const int r8   = lane >> 3;
    const int slot = lane & 7;
#pragma unroll
    for (int q = 0; q < 4; ++q) {
        const int blk   = q * 4 + w;
        const int row   = blk * 8 + r8;
        const int chunk = slot ^ (row & 7);
        gload16(src + (size_t)(rowBase + row) * 1024 + kt * 128 + chunk * 16,
                lds + blk * 1024);
    }
}

// ---------------------------------------------------------------------------
// gemm_fp8: d1 = relu((xq @ W1q^T) * (1/64) + b1), fp8 e4m3 MFMA.
// Tile 128x128, BK=128 (nK=8), 4 waves (2x2).  (Validated in R15.)
// ---------------------------------------------------------------------------
__global__ __launch_bounds__(256) void gemm_fp8(
    const unsigned char* __restrict__ A,    // 16384 x 1024 fp8
    const unsigned char* __restrict__ Bq,   // 512 x 1024 fp8 (N x K), x64
    const float* __restrict__ bias,         // b1 (500)
    unsigned short* __restrict__ C) {       // 16384 x 512 bf16
    constexpr int nK = 8;
    __shared__ unsigned char As[2][128 * 128];
    __shared__ unsigned char Bs[2][128 * 128];

    const int tid  = threadIdx.x;
    const int lane = tid & 63;
    const int wid  = tid >> 6;
    const int wm   = wid >> 1;
    const int wn   = wid & 1;
    const int g    = lane >> 4;
    const int r16  = lane & 15;

    const int cpx = gridDim.x >> 3;
    const int swz = (blockIdx.x & 7) * cpx + (blockIdx.x >> 3);
    const int rowBase = (swz >> 2) << 7;
    const int colBase = (swz & 3) << 7;

    f32x4 acc[4][4];
#pragma unroll
    for (int m = 0; m < 4; ++m)
#pragma unroll
        for (int n = 0; n < 4; ++n)
            acc[m][n] = (f32x4){0.f, 0.f, 0.f, 0.f};

    stage_fp8(A, rowBase, 0, As[0], wid, lane);
    stage_fp8(Bq, colBase, 0, Bs[0], wid, lane);
    asm volatile("s_waitcnt vmcnt(0)" ::: "memory");
    __builtin_amdgcn_s_barrier();
    asm volatile("" ::: "memory");

    for (int kt = 0; kt < nK; ++kt) {
        const int buf = kt & 1;
        if (kt + 1 < nK) {
            stage_fp8(A, rowBase, kt + 1, As[buf ^ 1], wid, lane);
            stage_fp8(Bq, colBase, kt + 1, Bs[buf ^ 1], wid, lane);
        }
        asm volatile("" ::: "memory");

        const unsigned char* Ab = As[buf];
        const unsigned char* Bb = Bs[buf];
#pragma unroll
        for (int ks = 0; ks < 4; ++ks) {
            long af[4], bf[4];
#pragma unroll
            for (int m = 0; m < 4; ++m) {
                const int row = wm * 64 + m * 16 + r16;
                const int byte = row * 128 +
                    ((((ks << 1) | (g >> 1)) ^ (row & 7)) << 4) + ((g & 1) << 3);
                af[m] = *(const long*)(Ab + byte);
            }
#pragma unroll
            for (int n = 0; n < 4; ++n) {
                const int row = wn * 64 + n * 16 + r16;
                const int byte = row * 128 +
                    ((((ks << 1) | (g >> 1)) ^ (row & 7)) << 4) + ((g & 1) << 3);
                bf[n] = *(const long*)(Bb + byte);
            }
#pragma unroll
            for (int m = 0; m < 4; ++m)
#pragma unroll
                for (int n = 0; n < 4; ++n)
                    acc[m][n] = __builtin_amdgcn_mfma_f32_16x16x32_fp8_fp8(
                        af[m], bf[n], acc[m][n], 0, 0, 0);
        }

        asm volatile("s_waitcnt vmcnt(0)" ::: "memory");
        __builtin_amdgcn_s_barrier();
        asm volatile("" ::: "memory");
    }

    unsigned short* Cb = (unsigned short*)As[0];
#pragma unroll
    for (int n = 0; n < 4; ++n) {
        const int lcol = wn * 64 + n * 16 + r16;
        const int col = colBase + lcol;
        const float bv = (col < 500) ? bias[col] : 0.f;
#pragma unroll
        for (int m = 0; m < 4; ++m) {
            const int lrow = wm * 64 + m * 16 + g * 4;
#pragma unroll
            for (int r = 0; r < 4; ++r) {
                float v = acc[m][n][r] * 0.015625f + bv;
                v = v > 0.f ? v : 0.f;
                Cb[(lrow + r) * 128 + lcol] = f2bf(v);
            }
        }
    }
    __syncthreads();

    {
        const int row  = tid >> 1;
        const int half = tid & 1;
        const uint4* s = (const uint4*)(Cb + row * 128 + half * 64);
        uint4* dd = (uint4*)(C + (size_t)(rowBase + row) * 512 + colBase + half * 64);
        dd[0] = s[0]; dd[1] = s[1]; dd[2] = s[2]; dd[3] = s[3];
    }
}

// ---------------------------------------------------------------------------
// stage8 (8-wave bf16 staging for tail_fused)
// ---------------------------------------------------------------------------
template <int ROWS>
static __device__ __forceinline__ void stage8(
    const unsigned short* __restrict__ src, int K, int rowBase, int kt,
    unsigned short* lds, int w, int lane) {
    const int r8   = lane >> 3;
    const int slot = lane & 7;
#pragma unroll
    for (int q = 0; q < ROWS / 64; ++q) {
        const int blk   = q * 8 + w;
        const int row   = blk * 8 + r8;
        const int chunk = slot ^ (row & 7);
        gload16(src + (size_t)(rowBase + row) * K + kt * 64 + chunk * 8,
                lds + blk * 512);
    }
}

// ---------------------------------------------------------------------------
// tail_fused (unchanged, validated): per 64-row block —
//   P = relu(d1 @ W2b^T + b2); acc2 = P @ W3b^T;
//   tail = relu(acc2+b3).Wl[1024:]; z_i = Horner(zparts,s)+czz_i+tail+bl.
// ---------------------------------------------------------------------------
__global__ __launch_bounds__(512) void tail_fused(
    const unsigned short* __restrict__ d1,
    const unsigned short* __restrict__ W2b, const float* __restrict__ b2,
    const unsigned short* __restrict__ W3b, const float* __restrict__ b3,
    const float* __restrict__ Wl, const float* __restrict__ bl,
    const float* __restrict__ zparts, const float* __restrict__ czz,
    float* __restrict__ out) {
    __shared__ unsigned short As[2][64 * 64];
    __shared__ unsigned short Bs[2][256 * 64];
    __shared__ unsigned short P[64 * 256];
    __shared__ float part[8][64];

    const int tid  = threadIdx.x;
    const int lane = tid & 63;
    const int wid  = tid >> 6;
    const int wm   = wid >> 2;
    const int wn   = wid & 3;
    const int g    = lane >> 4;
    const int r16  = lane & 15;
    const int rowBase = blockIdx.x << 6;

    f32x4 acc[2][4];
#pragma unroll
    for (int m = 0; m < 2; ++m)
#pragma unroll
        for (int n = 0; n < 4; ++n)
            acc[m][n] = (f32x4){0.f, 0.f, 0.f, 0.f};

    stage8<64>(d1, 512, rowBase, 0, As[0], wid, lane);
    stage8<256>(W2b, 512, 0, 0, Bs[0], wid, lane);

    for (int kt = 0; kt < 8; ++kt) {
        const int buf = kt & 1;
        if (kt + 1 < 8) {
            stage8<64>(d1, 512, rowBase, kt + 1, As[buf ^ 1], wid, lane);
            stage8<256>(W2b, 512, 0, kt + 1, Bs[buf ^ 1], wid, lane);
            asm volatile("s_waitcnt vmcnt(5)" ::: "memory");
        } else {
            asm volatile("s_waitcnt vmcnt(0)" ::: "memory");
        }
        __builtin_amdgcn_s_barrier();
        asm volatile("" ::: "memory");

        const unsigned short* Ab = As[buf];
        const unsigned short* Bb = Bs[buf];
#pragma unroll
        for (int ks = 0; ks < 2; ++ks) {
            s16x8 af[2], bfr[4];
#pragma unroll
            for (int m = 0; m < 2; ++m) {
                const int row = wm * 32 + m * 16 + r16;
                const int off = ((ks * 4 + g) * 16) ^ ((row & 7) << 4);
                af[m] = *(const s16x8*)((const char*)Ab + row * 128 + off);
            }
#pragma unroll
            for (int n = 0; n < 4; ++n) {
                const int row = wn * 64 + n * 16 + r16;
                const int off = ((ks * 4 + g) * 16) ^ ((row & 7) << 4);
                bfr[n] = *(const s16x8*)((const char*)Bb + row * 128 + off);
            }
#pragma unroll
            for (int m = 0; m < 2; ++m)
#pragma unroll
                for (int n = 0; n < 4; ++n)
                    acc[m][n] = __builtin_amdgcn_mfma_f32_16x16x32_bf16(af[m], bfr[n], acc[m][n], 0, 0, 0);
        }
        asm volatile("s_waitcnt lgkmcnt(0)" ::: "memory");
        __builtin_amdgcn_s_barrier();
        asm volatile("" ::: "memory");
    }

#pragma unroll
    for (int n = 0; n < 4; ++n) {
        const int col = wn * 64 + n * 16 + r16;
        const float bv = (col < 200) ? b2[col] : 0.f;
#pragma unroll
        for (int m = 0; m < 2; ++m) {
#pragma unroll
            for (int r = 0; r < 4; ++r) {
                const int row = wm * 32 + m * 16 + g * 4 + r;
                float v = acc[m][n][r] + bv;
                v = v > 0.f ? v : 0.f;
                const int byte = row * 512 + ((col * 2) ^ ((row & 7) << 4));
                *(unsigned short*)((char*)P + byte) = f2bf(v);
            }
        }
    }

    stage8<256>(W3b, 256, 0, 0, Bs[0], wid, lane);
    asm volatile("s_waitcnt lgkmcnt(0)" ::: "memory");
    __builtin_amdgcn_s_barrier();
    asm volatile("" ::: "memory");

    f32x4 acc2[2][4];
#pragma unroll
    for (int m = 0; m < 2; ++m)
#pragma unroll
        for (int n = 0; n < 4; ++n)
            acc2[m][n] = (f32x4){0.f, 0.f, 0.f, 0.f};

    for (int kt = 0; kt < 4; ++kt) {
        const int buf = kt & 1;
        if (kt + 1 < 4) {
            stage8<256>(W3b, 256, 0, kt + 1, Bs[buf ^ 1], wid, lane);
            asm volatile("s_waitcnt vmcnt(4)" ::: "memory");
        } else {
            asm volatile("s_waitcnt vmcnt(0)" ::: "memory");
        }
        __builtin_amdgcn_s_barrier();
        asm volatile("" ::: "memory");

        const unsigned short* Bb = Bs[buf];
#pragma unroll
        for (int ks = 0; ks < 2; ++ks) {
            s16x8 af[2], bfr[4];
#pragma unroll
            for (int m = 0; m < 2; ++m) {
                const int row = wm * 32 + m * 16 + r16;
                const int byte = row * 512 + ((kt * 128 + (ks * 4 + g) * 16) ^ ((row & 7) << 4));
                af[m] = *(const s16x8*)((const char*)P + byte);
            }
#pragma unroll
            for (int n = 0; n < 4; ++n) {
                const int row = wn * 64 + n * 16 + r16;
                const int off = ((ks * 4 + g) * 16) ^ ((row & 7) << 4);
                bfr[n] = *(const s16x8*)((const char*)Bb + row * 128 + off);
            }
#pragma unroll
            for (int m = 0; m < 2; ++m)
#pragma unroll
                for (int n = 0; n < 4; ++n)
                    acc2[m][n] = __builtin_amdgcn_mfma_f32_16x16x32_bf16(af[m], bfr[n], acc2[m][n], 0, 0, 0);
        }
        asm volatile("s_waitcnt lgkmcnt(0)" ::: "memory");
        __builtin_amdgcn_s_barrier();
        asm volatile("" ::: "memory");
    }

    float wlv[4], b3v[4];
#pragma unroll
    for (int n = 0; n < 4; ++n) {
        const int col = wn * 64 + n * 16 + r16;
        wlv[n] = (col < 200) ? Wl[1024 + col] : 0.f;
        b3v[n] = (col < 200) ? b3[col] : 0.f;
    }
#pragma unroll
    for (int m = 0; m < 2; ++m) {
#pragma unroll
        for (int r = 0; r < 4; ++r) {
            float s = 0.f;
#pragma unroll
            for (int n = 0; n < 4; ++n) {
                float v = acc2[m][n][r] + b3v[n];
                v = v > 0.f ? v : 0.f;
                s += v * wlv[n];
            }
            s += __shfl_xor(s, 1, 64);
            s += __shfl_xor(s, 2, 64);
            s += __shfl_xor(s, 4, 64);
            s += __shfl_xor(s, 8, 64);
            if (r16 == 0) part[wid][wm * 32 + m * 16 + g * 4 + r] = s;
        }
    }
    __syncthreads();

    if (tid < 64) {
        const int row = rowBase + tid;
        const int wmr = (tid >> 5) << 2;
        const float t = part[wmr][tid] + part[wmr + 1][tid] +
                        part[wmr + 2][tid] + part[wmr + 3][tid];
        const float blv = bl[0];
        const float* zp = zparts + (size_t)row * 8;
        float4 zpa = *(const float4*)(zp);       // P3_0 P2_0 P1_0 P3_1
        float4 zpb = *(const float4*)(zp + 4);   // P2_1 P1_1 P0   s
        const float s = zpb.w;
        const float z0 = ((zpa.x * s + zpa.y + czz[0]) * s + zpa.z + czz[1]) * s
                         + zpb.z + czz[2] + t + blv;
        const float z1 = ((zpa.w * s + zpb.x + czz[3]) * s + zpb.y + czz[4]) * s
                         + zpb.z + czz[5] + t + blv;
        out[row]          = 1.f / (1.f + expf(-z0));
        out[B_ROWS + row] = 1.f / (1.f + expf(-z1));
    }
}

// ---------------------------------------------------------------------------
extern "C" void kernel_launch(void* const* d_in, const int* in_sizes, int n_in,
                              void* d_out, int out_size, void* d_ws, size_t ws_size,
                              hipStream_t stream) {
    const float* x  = (const float*)d_in[0];
    const float* W1 = (const float*)d_in[3];
    const float* b1 = (const float*)d_in[4];
    const float* W2 = (const float*)d_in[5];
    const float* b2 = (const float*)d_in[6];
    const float* W3 = (const float*)d_in[7];
    const float* b3 = (const float*)d_in[8];
    const float* Wl = (const float*)d_in[9];
    const float* bl = (const float*)d_in[10];
    const float* cw = (const float*)d_in[11];
    const float* cb = (const float*)d_in[12];
    float* out = (float*)d_out;

    unsigned short* d1  = (unsigned short*)d_ws;          // 16384 x 512 bf16
    unsigned char*  xq  = (unsigned char*)(d1 + (size_t)16384 * 512);  // 16384 x 1024 fp8
    unsigned char*  W1q = xq + (size_t)16384 * 1024;      // 512 x 1024 fp8
    unsigned short* W2b = (unsigned short*)(W1q + (size_t)512 * 1024); // 256 x 512
    unsigned short* W3b = W2b + (size_t)256 * 512;        // 256 x 256
    float* zparts = (float*)(W3b + (size_t)256 * 256);    // 16384 x 8
    float* czz = zparts + (size_t)16384 * 8;              // 6

    // weights + exact f32 cross dots + x->fp8 (native cvt), one kernel
    xdots_prep<<<177 + 2048, 256, 0, stream>>>(
        x, W1, W2, W3, cw, cb, Wl, W1q, W2b, W3b, czz, xq, zparts);

    // d1 = relu((xq @ W1q) / 64 + b1), fp8 MFMA
    gemm_fp8<<<512, 256, 0, stream>>>(xq, W1q, b1, d1);

    // d2/d3/tail/cross-combine/sigmoid fused
    tail_fused<<<256, 512, 0, stream>>>(d1, W2b, b2, W3b, b3, Wl, bl,
                                        zparts, czz, out);
}